// Round 3
// baseline (702.814 us; speedup 1.0000x reference)
//
#include <hip/hip_runtime.h>

#define NS 64
#define HH 64
#define WW 64
#define VD 64
#define VH 64
#define VW 64
#define NVOX (VD*VH*VW)
#define NPIX (NS*HH*WW)
#define RES 1.5f
#define NTAB (NS*27)

#define SPLIT 4
#define SLC_PER (NS/SPLIT)      // 16
#define PAIRS (SLC_PER*27)      // 432
#define COLS_PER_BLK 8
#define COL_PAD 68

// ---------------------------------------------------------------
// Per-(slice,tap) affine table:  pos = w*U + h*V + C
// entry layout (16 floats):
//  [0..3]  a,b,c,d   : inverse of [[Ux,Vx],[Uy,Vy]]
//  [4..7]  Ux,Uy,Uz,Vx
//  [8..11] Vy,Vz,Cx,Cy
//  [12..15]Cz,psf_k,s*4096,0
// ---------------------------------------------------------------
__global__ __launch_bounds__(256) void k_setup(const float* __restrict__ tr,
                                               const float* __restrict__ psf,
                                               float* __restrict__ tab) {
    int i = blockIdx.x * 256 + threadIdx.x;
    if (i >= NTAB) return;
    int s = i / 27, k = i % 27;
    const float* p = tr + s * 12;
    float R00 = p[0], R01 = p[1], R02 = p[2],  t0 = p[3];
    float R10 = p[4], R11 = p[5], R12 = p[6],  t1 = p[7];
    float R20 = p[8], R21 = p[9], R22 = p[10], t2 = p[11];
    float Ux = RES * R00, Uy = RES * R10, Uz = RES * R20;
    float Vx = RES * R01, Vy = RES * R11, Vz = RES * R21;
    float ox = (float)(k % 3 - 1), oy = (float)((k / 3) % 3 - 1), oz = (float)(k / 9 - 1);
    float Cx = t0 + 31.5f + R00 * ox + R01 * oy + R02 * oz - 31.5f * (Ux + Vx);
    float Cy = t1 + 31.5f + R10 * ox + R11 * oy + R12 * oz - 31.5f * (Uy + Vy);
    float Cz = t2 + 31.5f + R20 * ox + R21 * oy + R22 * oz - 31.5f * (Uz + Vz);
    float inv = 1.f / (Ux * Vy - Uy * Vx);
    float* e = tab + i * 16;
    e[0] = Vy * inv;  e[1] = -Vx * inv; e[2] = -Uy * inv; e[3] = Ux * inv;
    e[4] = Ux; e[5] = Uy; e[6] = Uz; e[7] = Vx;
    e[8] = Vy; e[9] = Vz; e[10] = Cx; e[11] = Cy;
    e[12] = Cz; e[13] = psf[k]; e[14] = (float)(s * 4096); e[15] = 0.f;
}

// ---------------------------------------------------------------
// Forward projection A: per pixel, 27 taps x trilinear gather
// ---------------------------------------------------------------
__device__ __forceinline__ float trilin_gather(const float* __restrict__ vol,
                                               float px, float py, float pz) {
    float x0 = floorf(px), y0 = floorf(py), z0 = floorf(pz);
    float fx = px - x0, fy = py - y0, fz = pz - z0;
    int ix = (int)x0, iy = (int)y0, iz = (int)z0;
    float acc = 0.f;
#pragma unroll
    for (int dz = 0; dz < 2; ++dz) {
        float wz = dz ? fz : 1.f - fz;
        int zi = iz + dz;
#pragma unroll
        for (int dy = 0; dy < 2; ++dy) {
            float wy = dy ? fy : 1.f - fy;
            int yi = iy + dy;
#pragma unroll
            for (int dx = 0; dx < 2; ++dx) {
                float wx = dx ? fx : 1.f - fx;
                int xi = ix + dx;
                bool valid = (xi >= 0) & (xi < VW) & (yi >= 0) & (yi < VH) & (zi >= 0) & (zi < VD);
                if (valid) acc = fmaf(wx * wy * wz, vol[(zi * VH + yi) * VW + xi], acc);
            }
        }
    }
    return acc;
}

__global__ __launch_bounds__(256) void k_a(const float* __restrict__ vin,
                                           float* __restrict__ g,
                                           const float* __restrict__ tr,
                                           const float* __restrict__ psf) {
    __shared__ float s_psf[27];
    if (threadIdx.x < 27) s_psf[threadIdx.x] = psf[threadIdx.x];
    __syncthreads();
    int gid = blockIdx.x * 256 + threadIdx.x;
    int s = gid >> 12;
    int pix = gid & 4095;
    int h = pix >> 6, w = pix & 63;
    const float* p = tr + s * 12;
    float R0 = p[0], R1 = p[1], R2 = p[2],  t0 = p[3];
    float R3 = p[4], R4 = p[5], R5 = p[6],  t1 = p[7];
    float R6 = p[8], R7 = p[9], R8 = p[10], t2 = p[11];
    float xs = ((float)w - 31.5f) * RES;
    float ys = ((float)h - 31.5f) * RES;
    float p0x = fmaf(R0, xs, fmaf(R1, ys, t0)) + 31.5f;
    float p0y = fmaf(R3, xs, fmaf(R4, ys, t1)) + 31.5f;
    float p0z = fmaf(R6, xs, fmaf(R7, ys, t2)) + 31.5f;
    float a = 0.f;
#pragma unroll
    for (int k = 0; k < 27; ++k) {
        float ox = (float)(k % 3 - 1), oy = (float)((k / 3) % 3 - 1), oz = (float)(k / 9 - 1);
        float px = p0x + ox * R0 + oy * R1 + oz * R2;
        float py = p0y + ox * R3 + oy * R4 + oz * R5;
        float pz = p0z + ox * R6 + oy * R7 + oz * R8;
        a = fmaf(s_psf[k], trilin_gather(vin, px, py, pz), a);
    }
    g[gid] = a;
}

// ---------------------------------------------------------------
// Adjoint At as a PURE GATHER over voxel columns, slice-split 4-way.
// Block b: split = b & 3 (slices [split*16, split*16+16)),
//          colblk = b >> 2 (8 columns). 256 thr = 8 cols x 32 pair-groups.
// Output: part[split*NVOX + vox] (partial volumes, summed by consumers).
// ---------------------------------------------------------------
__global__ __launch_bounds__(256) void k_atg(const float* __restrict__ g,
                                             float* __restrict__ part,
                                             const float* __restrict__ tab) {
    __shared__ float cols[COLS_PER_BLK][COL_PAD];
    for (int i = threadIdx.x; i < COLS_PER_BLK * COL_PAD; i += 256)
        (&cols[0][0])[i] = 0.f;
    __syncthreads();

    int split = blockIdx.x & (SPLIT - 1);
    int colblk = blockIdx.x >> 2;
    int col0 = colblk * COLS_PER_BLK;
    int lc = threadIdx.x & 7;
    int sg = threadIdx.x >> 3;        // 0..31
    int col = col0 + lc;
    int yi = col >> 6, xi = col & 63;
    float X = (float)xi, Y = (float)yi;

    const float* tbase = tab + split * SLC_PER * 27 * 16;

    for (int idx = sg; idx < PAIRS; idx += 32) {
        const float* e = tbase + idx * 16;
        float4 e0 = *(const float4*)(e);
        float4 e1 = *(const float4*)(e + 4);
        float4 e2 = *(const float4*)(e + 8);
        float4 e3 = *(const float4*)(e + 12);
        float a = e0.x, b = e0.y, c = e0.z, d = e0.w;
        float Ux = e1.x, Uy = e1.y, Uz = e1.z, Vx = e1.w;
        float Vy = e2.x, Vz = e2.y, Cx = e2.z, Cy = e2.w;
        float Cz = e3.x, psfk = e3.y;
        int gbase = (int)e3.z;        // s*4096
        float rx = X - Cx, ry = Y - Cy;
        float ws = a * rx + b * ry;
        float hs = c * rx + d * ry;
        int w0 = (int)floorf(ws), h0 = (int)floorf(hs);
#pragma unroll
        for (int dh = 0; dh < 2; ++dh) {
            int h = h0 + dh;
            if ((unsigned)h >= 64u) continue;
            float fh = (float)h;
#pragma unroll
            for (int dw = 0; dw < 2; ++dw) {
                int w = w0 + dw;
                if ((unsigned)w >= 64u) continue;
                float fw = (float)w;
                float ddx = fmaf(fw, Ux, fmaf(fh, Vx, Cx)) - X;
                float ddy = fmaf(fw, Uy, fmaf(fh, Vy, Cy)) - Y;
                float wx = 1.f - fabsf(ddx);
                float wy = 1.f - fabsf(ddy);
                if (wx <= 0.f || wy <= 0.f) continue;
                float pz = fmaf(fw, Uz, fmaf(fh, Vz, Cz));
                float z0f = floorf(pz);
                float fz = pz - z0f;
                int z0 = (int)z0f;
                float val = wx * wy * psfk * g[gbase + (h << 6) + w];
                if ((unsigned)z0 < 64u) atomicAdd(&cols[lc][z0], val * (1.f - fz));
                int z1 = z0 + 1;
                if ((unsigned)z1 < 64u) atomicAdd(&cols[lc][z1], val * fz);
            }
        }
    }
    __syncthreads();
    float* pout = part + split * NVOX;
    for (int i = threadIdx.x; i < COLS_PER_BLK * 64; i += 256) {
        int lc2 = i & 7;
        int z = i >> 3;
        int col2 = col0 + lc2;
        pout[(z << 12) + col2] = cols[lc2][z];
    }
}

// ---------------- reductions & CG updates ----------------

__device__ __forceinline__ void block_reduce_atomic(float v, float* dst) {
#pragma unroll
    for (int off = 32; off > 0; off >>= 1) v += __shfl_down(v, off, 64);
    __shared__ float s_red[4];
    int lane = threadIdx.x & 63, wid = threadIdx.x >> 6;
    if (lane == 0) s_red[wid] = v;
    __syncthreads();
    if (threadIdx.x == 0) atomicAdd(dst, s_red[0] + s_red[1] + s_red[2] + s_red[3]);
}

__device__ __forceinline__ float sum4(const float* __restrict__ part, int i) {
    return (part[i] + part[NVOX + i]) + (part[2 * NVOX + i] + part[3 * NVOX + i]);
}

// r = b - sum(partAp) ; p = r ; scal[0] += r.r
__global__ __launch_bounds__(256) void k_residual4(const float* __restrict__ b,
                                                   const float* __restrict__ part,
                                                   float* __restrict__ r,
                                                   float* __restrict__ p,
                                                   float* __restrict__ scal) {
    int i = blockIdx.x * 256 + threadIdx.x;
    float rv = b[i] - sum4(part, i);
    r[i] = rv;
    p[i] = rv;
    block_reduce_atomic(rv * rv, &scal[0]);
}

// vol_b = sum(part)
__global__ __launch_bounds__(256) void k_reduce4(const float* __restrict__ part,
                                                 float* __restrict__ vout) {
    int i = blockIdx.x * 256 + threadIdx.x;
    vout[i] = sum4(part, i);
}

// Ap = sum(part); scal[1] += p.Ap
__global__ __launch_bounds__(256) void k_dot_reduce(const float* __restrict__ part,
                                                    const float* __restrict__ p,
                                                    float* __restrict__ Ap,
                                                    float* __restrict__ dst) {
    int i = blockIdx.x * 256 + threadIdx.x;
    float apv = sum4(part, i);
    Ap[i] = apv;
    block_reduce_atomic(p[i] * apv, dst);
}

// scal[3] += p . sum(part)   (no Ap write needed on last iter)
__global__ __launch_bounds__(256) void k_dot4(const float* __restrict__ part,
                                              const float* __restrict__ p,
                                              float* __restrict__ dst) {
    int i = blockIdx.x * 256 + threadIdx.x;
    block_reduce_atomic(p[i] * sum4(part, i), dst);
}

// alpha = scal[0]/scal[1]; x_out = x_in + alpha p; r -= alpha Ap; scal[2] += r.r
__global__ __launch_bounds__(256) void k_update_xr(const float* __restrict__ x_in,
                                                   float* __restrict__ x_out,
                                                   float* __restrict__ r,
                                                   const float* __restrict__ p,
                                                   const float* __restrict__ Ap,
                                                   float* __restrict__ scal) {
    int i = blockIdx.x * 256 + threadIdx.x;
    float alpha = scal[0] / scal[1];
    x_out[i] = fmaf(alpha, p[i], x_in[i]);
    float rv = fmaf(-alpha, Ap[i], r[i]);
    r[i] = rv;
    block_reduce_atomic(rv * rv, &scal[2]);
}

__global__ __launch_bounds__(256) void k_update_p(float* __restrict__ p,
                                                  const float* __restrict__ r,
                                                  const float* __restrict__ scal) {
    int i = blockIdx.x * 256 + threadIdx.x;
    float beta = scal[2] / scal[0];
    p[i] = fmaf(beta, p[i], r[i]);
}

__global__ __launch_bounds__(256) void k_final(const float* __restrict__ x,
                                               const float* __restrict__ p,
                                               const float* __restrict__ scal,
                                               float* __restrict__ out) {
    int i = blockIdx.x * 256 + threadIdx.x;
    float alpha = scal[2] / scal[3];
    float v = fmaf(alpha, p[i], x[i]);
    out[i] = v > 0.f ? v : 0.f;
}

extern "C" void kernel_launch(void* const* d_in, const int* in_sizes, int n_in,
                              void* d_out, int out_size, void* d_ws, size_t ws_size,
                              hipStream_t stream) {
    const float* transforms = (const float*)d_in[0];
    const float* slices     = (const float*)d_in[1];
    const float* volume     = (const float*)d_in[2];
    const float* psf        = (const float*)d_in[3];
    float* out = (float*)d_out;

    float* tab    = (float*)d_ws;             // 1728*16 floats
    float* part   = tab    + NTAB * 16;       // 4*NVOX
    float* vol_b  = part   + SPLIT * NVOX;
    float* vol_x  = vol_b  + NVOX;
    float* vol_r  = vol_x  + NVOX;
    float* vol_p  = vol_r  + NVOX;
    float* vol_Ap = vol_p  + NVOX;
    float* gbuf   = vol_Ap + NVOX;
    float* scal   = gbuf   + NPIX;            // 4 floats

    const int nblk = NPIX / 256;                        // 1024
    const int ablk = (NVOX / 64) / COLS_PER_BLK * SPLIT; // 2048

    hipMemsetAsync(scal, 0, 4 * sizeof(float), stream);

    k_setup<<<(NTAB + 255) / 256, 256, 0, stream>>>(transforms, psf, tab);

    // b = At(slices)
    k_atg<<<ablk, 256, 0, stream>>>(slices, part, tab);
    k_reduce4<<<NVOX / 256, 256, 0, stream>>>(part, vol_b);

    // Ap = AtA(x0=volume); r = b - Ap; p = r; rr0
    k_a<<<nblk, 256, 0, stream>>>(volume, gbuf, transforms, psf);
    k_atg<<<ablk, 256, 0, stream>>>(gbuf, part, tab);
    k_residual4<<<NVOX / 256, 256, 0, stream>>>(vol_b, part, vol_r, vol_p, scal);

    // iter 0
    k_a<<<nblk, 256, 0, stream>>>(vol_p, gbuf, transforms, psf);
    k_atg<<<ablk, 256, 0, stream>>>(gbuf, part, tab);
    k_dot_reduce<<<NVOX / 256, 256, 0, stream>>>(part, vol_p, vol_Ap, &scal[1]);
    k_update_xr<<<NVOX / 256, 256, 0, stream>>>(volume, vol_x, vol_r, vol_p, vol_Ap, scal);
    k_update_p<<<NVOX / 256, 256, 0, stream>>>(vol_p, vol_r, scal);

    // iter 1
    k_a<<<nblk, 256, 0, stream>>>(vol_p, gbuf, transforms, psf);
    k_atg<<<ablk, 256, 0, stream>>>(gbuf, part, tab);
    k_dot4<<<NVOX / 256, 256, 0, stream>>>(part, vol_p, &scal[3]);
    k_final<<<NVOX / 256, 256, 0, stream>>>(vol_x, vol_p, scal, out);
}

// Round 4
// 388.801 us; speedup vs baseline: 1.8076x; 1.8076x over previous
//
#include <hip/hip_runtime.h>

#define NS 64
#define HH 64
#define WW 64
#define VD 64
#define VH 64
#define VW 64
#define NVOX (VD*VH*VW)
#define NPIX (NS*HH*WW)
#define RES 1.5f
#define NTAB (NS*27)
#define WIN 10

// ---------------------------------------------------------------
// Per-(slice,tap) affine table:  pos = w*U + h*V + C
// entry layout (16 floats):
//  [0..3]  a,b,c,d   : inverse of [[Ux,Vx],[Uy,Vy]]
//  [4..7]  Ux,Uy,Uz,Vx
//  [8..11] Vy,Vz,Cx,Cy
//  [12..15]Cz,psf_k,0,0
// ---------------------------------------------------------------
__global__ __launch_bounds__(256) void k_setup(const float* __restrict__ tr,
                                               const float* __restrict__ psf,
                                               float* __restrict__ tab) {
    int i = blockIdx.x * 256 + threadIdx.x;
    if (i >= NTAB) return;
    int s = i / 27, k = i % 27;
    const float* p = tr + s * 12;
    float R00 = p[0], R01 = p[1], R02 = p[2],  t0 = p[3];
    float R10 = p[4], R11 = p[5], R12 = p[6],  t1 = p[7];
    float R20 = p[8], R21 = p[9], R22 = p[10], t2 = p[11];
    float Ux = RES * R00, Uy = RES * R10, Uz = RES * R20;
    float Vx = RES * R01, Vy = RES * R11, Vz = RES * R21;
    float ox = (float)(k % 3 - 1), oy = (float)((k / 3) % 3 - 1), oz = (float)(k / 9 - 1);
    float Cx = t0 + 31.5f + R00 * ox + R01 * oy + R02 * oz - 31.5f * (Ux + Vx);
    float Cy = t1 + 31.5f + R10 * ox + R11 * oy + R12 * oz - 31.5f * (Uy + Vy);
    float Cz = t2 + 31.5f + R20 * ox + R21 * oy + R22 * oz - 31.5f * (Uz + Vz);
    float inv = 1.f / (Ux * Vy - Uy * Vx);
    float* e = tab + i * 16;
    e[0] = Vy * inv;  e[1] = -Vx * inv; e[2] = -Uy * inv; e[3] = Ux * inv;
    e[4] = Ux; e[5] = Uy; e[6] = Uz; e[7] = Vx;
    e[8] = Vy; e[9] = Vz; e[10] = Cx; e[11] = Cy;
    e[12] = Cz; e[13] = psf[k]; e[14] = 0.f; e[15] = 0.f;
}

// ---------------------------------------------------------------
// Forward projection A: per pixel, 27 taps x trilinear gather
// ---------------------------------------------------------------
__device__ __forceinline__ float trilin_gather(const float* __restrict__ vol,
                                               float px, float py, float pz) {
    float x0 = floorf(px), y0 = floorf(py), z0 = floorf(pz);
    float fx = px - x0, fy = py - y0, fz = pz - z0;
    int ix = (int)x0, iy = (int)y0, iz = (int)z0;
    float acc = 0.f;
#pragma unroll
    for (int dz = 0; dz < 2; ++dz) {
        float wz = dz ? fz : 1.f - fz;
        int zi = iz + dz;
#pragma unroll
        for (int dy = 0; dy < 2; ++dy) {
            float wy = dy ? fy : 1.f - fy;
            int yi = iy + dy;
#pragma unroll
            for (int dx = 0; dx < 2; ++dx) {
                float wx = dx ? fx : 1.f - fx;
                int xi = ix + dx;
                bool valid = (xi >= 0) & (xi < VW) & (yi >= 0) & (yi < VH) & (zi >= 0) & (zi < VD);
                if (valid) acc = fmaf(wx * wy * wz, vol[(zi * VH + yi) * VW + xi], acc);
            }
        }
    }
    return acc;
}

__global__ __launch_bounds__(256) void k_a(const float* __restrict__ vin,
                                           float* __restrict__ g,
                                           const float* __restrict__ tr,
                                           const float* __restrict__ psf) {
    __shared__ float s_psf[27];
    if (threadIdx.x < 27) s_psf[threadIdx.x] = psf[threadIdx.x];
    __syncthreads();
    int gid = blockIdx.x * 256 + threadIdx.x;
    int s = gid >> 12;
    int pix = gid & 4095;
    int h = pix >> 6, w = pix & 63;
    const float* p = tr + s * 12;
    float R0 = p[0], R1 = p[1], R2 = p[2],  t0 = p[3];
    float R3 = p[4], R4 = p[5], R5 = p[6],  t1 = p[7];
    float R6 = p[8], R7 = p[9], R8 = p[10], t2 = p[11];
    float xs = ((float)w - 31.5f) * RES;
    float ys = ((float)h - 31.5f) * RES;
    float p0x = fmaf(R0, xs, fmaf(R1, ys, t0)) + 31.5f;
    float p0y = fmaf(R3, xs, fmaf(R4, ys, t1)) + 31.5f;
    float p0z = fmaf(R6, xs, fmaf(R7, ys, t2)) + 31.5f;
    float a = 0.f;
#pragma unroll
    for (int k = 0; k < 27; ++k) {
        float ox = (float)(k % 3 - 1), oy = (float)((k / 3) % 3 - 1), oz = (float)(k / 9 - 1);
        float px = p0x + ox * R0 + oy * R1 + oz * R2;
        float py = p0y + ox * R3 + oy * R4 + oz * R5;
        float pz = p0z + ox * R6 + oy * R7 + oz * R8;
        a = fmaf(s_psf[k], trilin_gather(vin, px, py, pz), a);
    }
    g[gid] = a;
}

// ---------------------------------------------------------------
// Adjoint At: gather over voxel columns with per-(col,slice)
// REGISTER z-window (10 wide). Block = 4 columns x 64 slices.
// Each thread: 27 taps -> acc[10] in regs -> 10 LDS atomics.
// Output complete per block: direct write, no partials.
// ---------------------------------------------------------------
__global__ __launch_bounds__(256) void k_atv(const float* __restrict__ g,
                                             float* __restrict__ vout,
                                             const float* __restrict__ tab) {
    __shared__ float cols[4][68];
    for (int i = threadIdx.x; i < 4 * 68; i += 256) (&cols[0][0])[i] = 0.f;
    __syncthreads();

    int lc = threadIdx.x & 3;
    int s  = threadIdx.x >> 2;          // 0..63
    int col0 = blockIdx.x * 4;
    int col = col0 + lc;
    float X = (float)(col & 63), Y = (float)(col >> 6);

    const float* tbase = tab + s * 27 * 16;
    int gbase = s << 12;

    // window base from center tap (k=13): z of slice plane at this column
    const float* ec = tbase + 13 * 16;
    float4 c0 = *(const float4*)(ec);
    float4 c1 = *(const float4*)(ec + 4);
    float4 c2 = *(const float4*)(ec + 8);
    float4 c3 = *(const float4*)(ec + 12);
    float rxc = X - c2.z, ryc = Y - c2.w;
    float wsc = c0.x * rxc + c0.y * ryc;
    float hsc = c0.z * rxc + c0.w * ryc;
    float pzc = fmaf(wsc, c1.z, fmaf(hsc, c2.y, c3.x));
    float basef = floorf(pzc) - 4.f;
    int   basei = (int)basef;

    float acc[WIN];
#pragma unroll
    for (int j = 0; j < WIN; ++j) acc[j] = 0.f;

    for (int k = 0; k < 27; ++k) {
        const float* e = tbase + k * 16;
        float4 e0 = *(const float4*)(e);
        float4 e1 = *(const float4*)(e + 4);
        float4 e2 = *(const float4*)(e + 8);
        float4 e3 = *(const float4*)(e + 12);
        float Ux = e1.x, Uy = e1.y, Uz = e1.z, Vx = e1.w;
        float Vy = e2.x, Vz = e2.y;
        float Cxr = e2.z - X, Cyr = e2.w - Y;   // C - voxel(x,y)
        float psfk = e3.y;
        float ws = e0.x * (-Cxr) + e0.y * (-Cyr);
        float hs = e0.z * (-Cxr) + e0.w * (-Cyr);
        float w0f = floorf(ws), h0f = floorf(hs);
        int w0 = (int)w0f, h0 = (int)h0f;
#pragma unroll
        for (int dh = 0; dh < 2; ++dh) {
            float fh = h0f + (float)dh;
            int hi = h0 + dh;
            int hok = ((unsigned)hi < 64u) ? 1 : 0;
            int hc = min(max(hi, 0), 63);
            float tx = fmaf(fh, Vx, Cxr);
            float ty = fmaf(fh, Vy, Cyr);
            float tz = fmaf(fh, Vz, e3.x);
#pragma unroll
            for (int dw = 0; dw < 2; ++dw) {
                float fw = w0f + (float)dw;
                int wi = w0 + dw;
                int ok = ((unsigned)wi < 64u) ? hok : 0;
                int wc = min(max(wi, 0), 63);
                float ddx = fmaf(fw, Ux, tx);         // px - X
                float ddy = fmaf(fw, Uy, ty);         // py - Y
                float wx = fmaxf(0.f, 1.f - fabsf(ddx));
                float wy = fmaxf(0.f, 1.f - fabsf(ddy));
                float gv = g[gbase + (hc << 6) + wc];
                float val = ok ? (wx * wy * psfk * gv) : 0.f;
                float prel = fmaf(fw, Uz, tz) - basef; // pz - base
#pragma unroll
                for (int j = 0; j < WIN; ++j) {
                    float t = fmaxf(0.f, 1.f - fabsf(prel - (float)j));
                    acc[j] = fmaf(val, t, acc[j]);
                }
            }
        }
    }

    // flush window -> LDS (10 atomics per thread)
#pragma unroll
    for (int j = 0; j < WIN; ++j) {
        int zj = basei + j;
        int ok = ((unsigned)zj < 64u);
        int zc = min(max(zj, 0), 63);
        atomicAdd(&cols[lc][zc], ok ? acc[j] : 0.f);
    }
    __syncthreads();

    int z = threadIdx.x >> 2;
    int l2 = threadIdx.x & 3;
    vout[(z << 12) + col0 + l2] = cols[l2][z];
}

// ---------------- reductions & CG updates ----------------

__device__ __forceinline__ void block_reduce_atomic(float v, float* dst) {
#pragma unroll
    for (int off = 32; off > 0; off >>= 1) v += __shfl_down(v, off, 64);
    __shared__ float s_red[4];
    int lane = threadIdx.x & 63, wid = threadIdx.x >> 6;
    if (lane == 0) s_red[wid] = v;
    __syncthreads();
    if (threadIdx.x == 0) atomicAdd(dst, s_red[0] + s_red[1] + s_red[2] + s_red[3]);
}

__global__ __launch_bounds__(256) void k_residual(const float* __restrict__ b,
                                                  const float* __restrict__ Ap,
                                                  float* __restrict__ r,
                                                  float* __restrict__ p,
                                                  float* __restrict__ scal) {
    int i = blockIdx.x * 256 + threadIdx.x;
    float rv = b[i] - Ap[i];
    r[i] = rv;
    p[i] = rv;
    block_reduce_atomic(rv * rv, &scal[0]);
}

__global__ __launch_bounds__(256) void k_dot(const float* __restrict__ a,
                                             const float* __restrict__ b,
                                             float* __restrict__ dst) {
    int i = blockIdx.x * 256 + threadIdx.x;
    block_reduce_atomic(a[i] * b[i], dst);
}

// alpha = scal[0]/scal[1]; x_out = x_in + alpha p; r -= alpha Ap; scal[2] += r.r
__global__ __launch_bounds__(256) void k_update_xr(const float* __restrict__ x_in,
                                                   float* __restrict__ x_out,
                                                   float* __restrict__ r,
                                                   const float* __restrict__ p,
                                                   const float* __restrict__ Ap,
                                                   float* __restrict__ scal) {
    int i = blockIdx.x * 256 + threadIdx.x;
    float alpha = scal[0] / scal[1];
    x_out[i] = fmaf(alpha, p[i], x_in[i]);
    float rv = fmaf(-alpha, Ap[i], r[i]);
    r[i] = rv;
    block_reduce_atomic(rv * rv, &scal[2]);
}

__global__ __launch_bounds__(256) void k_update_p(float* __restrict__ p,
                                                  const float* __restrict__ r,
                                                  const float* __restrict__ scal) {
    int i = blockIdx.x * 256 + threadIdx.x;
    float beta = scal[2] / scal[0];
    p[i] = fmaf(beta, p[i], r[i]);
}

__global__ __launch_bounds__(256) void k_final(const float* __restrict__ x,
                                               const float* __restrict__ p,
                                               const float* __restrict__ scal,
                                               float* __restrict__ out) {
    int i = blockIdx.x * 256 + threadIdx.x;
    float alpha = scal[2] / scal[3];
    float v = fmaf(alpha, p[i], x[i]);
    out[i] = v > 0.f ? v : 0.f;
}

extern "C" void kernel_launch(void* const* d_in, const int* in_sizes, int n_in,
                              void* d_out, int out_size, void* d_ws, size_t ws_size,
                              hipStream_t stream) {
    const float* transforms = (const float*)d_in[0];
    const float* slices     = (const float*)d_in[1];
    const float* volume     = (const float*)d_in[2];
    const float* psf        = (const float*)d_in[3];
    float* out = (float*)d_out;

    float* tab    = (float*)d_ws;             // 1728*16 floats
    float* vol_b  = tab    + NTAB * 16;
    float* vol_x  = vol_b  + NVOX;
    float* vol_r  = vol_x  + NVOX;
    float* vol_p  = vol_r  + NVOX;
    float* vol_Ap = vol_p  + NVOX;
    float* gbuf   = vol_Ap + NVOX;
    float* scal   = gbuf   + NPIX;            // 4 floats

    const int nblk = NPIX / 256;              // 1024 (k_a)
    const int ablk = (NVOX / 64) / 4;         // 1024 (k_atv: 4 cols/block)

    hipMemsetAsync(scal, 0, 4 * sizeof(float), stream);

    k_setup<<<(NTAB + 255) / 256, 256, 0, stream>>>(transforms, psf, tab);

    // b = At(slices)
    k_atv<<<ablk, 256, 0, stream>>>(slices, vol_b, tab);

    // Ap = AtA(x0=volume); r = b - Ap; p = r; rr0
    k_a<<<nblk, 256, 0, stream>>>(volume, gbuf, transforms, psf);
    k_atv<<<ablk, 256, 0, stream>>>(gbuf, vol_Ap, tab);
    k_residual<<<NVOX / 256, 256, 0, stream>>>(vol_b, vol_Ap, vol_r, vol_p, scal);

    // iter 0
    k_a<<<nblk, 256, 0, stream>>>(vol_p, gbuf, transforms, psf);
    k_atv<<<ablk, 256, 0, stream>>>(gbuf, vol_Ap, tab);
    k_dot<<<NVOX / 256, 256, 0, stream>>>(vol_p, vol_Ap, &scal[1]);
    k_update_xr<<<NVOX / 256, 256, 0, stream>>>(volume, vol_x, vol_r, vol_p, vol_Ap, scal);
    k_update_p<<<NVOX / 256, 256, 0, stream>>>(vol_p, vol_r, scal);

    // iter 1
    k_a<<<nblk, 256, 0, stream>>>(vol_p, gbuf, transforms, psf);
    k_atv<<<ablk, 256, 0, stream>>>(gbuf, vol_Ap, tab);
    k_dot<<<NVOX / 256, 256, 0, stream>>>(vol_p, vol_Ap, &scal[3]);
    k_final<<<NVOX / 256, 256, 0, stream>>>(vol_x, vol_p, scal, out);
}

// Round 5
// 322.527 us; speedup vs baseline: 2.1791x; 1.2055x over previous
//
#include <hip/hip_runtime.h>

#define NS 64
#define HH 64
#define WW 64
#define VD 64
#define VH 64
#define VW 64
#define NVOX (VD*VH*VW)
#define NPIX (NS*HH*WW)
#define RES 1.5f
#define NTAB (NS*27)
#define WIN 6

// ---------------------------------------------------------------
// Per-(slice,tap) affine table:  pos = w*U + h*V + C
// entry layout (16 floats):
//  [0..3]  a,b,c,d   : inverse of [[Ux,Vx],[Uy,Vy]]
//  [4..7]  Ux,Uy,Uz,Vx
//  [8..11] Vy,Vz,Cx,Cy
//  [12..15]Cz,psf_k,0,0
// ---------------------------------------------------------------
__global__ __launch_bounds__(256) void k_setup(const float* __restrict__ tr,
                                               const float* __restrict__ psf,
                                               float* __restrict__ tab) {
    int i = blockIdx.x * 256 + threadIdx.x;
    if (i >= NTAB) return;
    int s = i / 27, k = i % 27;
    const float* p = tr + s * 12;
    float R00 = p[0], R01 = p[1], R02 = p[2],  t0 = p[3];
    float R10 = p[4], R11 = p[5], R12 = p[6],  t1 = p[7];
    float R20 = p[8], R21 = p[9], R22 = p[10], t2 = p[11];
    float Ux = RES * R00, Uy = RES * R10, Uz = RES * R20;
    float Vx = RES * R01, Vy = RES * R11, Vz = RES * R21;
    float ox = (float)(k % 3 - 1), oy = (float)((k / 3) % 3 - 1), oz = (float)(k / 9 - 1);
    float Cx = t0 + 31.5f + R00 * ox + R01 * oy + R02 * oz - 31.5f * (Ux + Vx);
    float Cy = t1 + 31.5f + R10 * ox + R11 * oy + R12 * oz - 31.5f * (Uy + Vy);
    float Cz = t2 + 31.5f + R20 * ox + R21 * oy + R22 * oz - 31.5f * (Uz + Vz);
    float inv = 1.f / (Ux * Vy - Uy * Vx);
    float* e = tab + i * 16;
    e[0] = Vy * inv;  e[1] = -Vx * inv; e[2] = -Uy * inv; e[3] = Ux * inv;
    e[4] = Ux; e[5] = Uy; e[6] = Uz; e[7] = Vx;
    e[8] = Vy; e[9] = Vz; e[10] = Cx; e[11] = Cy;
    e[12] = Cz; e[13] = psf[k]; e[14] = 0.f; e[15] = 0.f;
}

// ---------------------------------------------------------------
// Branch-free trilinear gather: clamped addresses, zeroed weights.
// ---------------------------------------------------------------
__device__ __forceinline__ float trilin_gather_bf(const float* __restrict__ vol,
                                                  float px, float py, float pz) {
    float x0 = floorf(px), y0 = floorf(py), z0 = floorf(pz);
    float fx = px - x0, fy = py - y0, fz = pz - z0;
    int ix = (int)x0, iy = (int)y0, iz = (int)z0;

    float wx0 = ((unsigned)ix       < 64u) ? (1.f - fx) : 0.f;
    float wx1 = ((unsigned)(ix + 1) < 64u) ? fx         : 0.f;
    float wy0 = ((unsigned)iy       < 64u) ? (1.f - fy) : 0.f;
    float wy1 = ((unsigned)(iy + 1) < 64u) ? fy         : 0.f;
    float wz0 = ((unsigned)iz       < 64u) ? (1.f - fz) : 0.f;
    float wz1 = ((unsigned)(iz + 1) < 64u) ? fz         : 0.f;

    int xc0 = min(max(ix, 0), 63),     xc1 = min(max(ix + 1, 0), 63);
    int yc0 = min(max(iy, 0), 63) << 6,  yc1 = min(max(iy + 1, 0), 63) << 6;
    int zc0 = min(max(iz, 0), 63) << 12, zc1 = min(max(iz + 1, 0), 63) << 12;

    float v000 = vol[zc0 + yc0 + xc0], v001 = vol[zc0 + yc0 + xc1];
    float v010 = vol[zc0 + yc1 + xc0], v011 = vol[zc0 + yc1 + xc1];
    float v100 = vol[zc1 + yc0 + xc0], v101 = vol[zc1 + yc0 + xc1];
    float v110 = vol[zc1 + yc1 + xc0], v111 = vol[zc1 + yc1 + xc1];

    float w00 = wx0 * wy0, w01 = wx1 * wy0, w10 = wx0 * wy1, w11 = wx1 * wy1;
    float lo = fmaf(w00, v000, fmaf(w01, v001, fmaf(w10, v010, w11 * v011)));
    float hi = fmaf(w00, v100, fmaf(w01, v101, fmaf(w10, v110, w11 * v111)));
    return fmaf(wz0, lo, wz1 * hi);
}

// ---------------------------------------------------------------
// Forward projection A: 4 lanes per pixel, taps k = q + 4*j.
// grid = NPIX*4/256 = 4096 blocks.
// ---------------------------------------------------------------
__global__ __launch_bounds__(256) void k_a(const float* __restrict__ vin,
                                           float* __restrict__ g,
                                           const float* __restrict__ tr,
                                           const float* __restrict__ psf) {
    __shared__ float s_psf[27];
    if (threadIdx.x < 27) s_psf[threadIdx.x] = psf[threadIdx.x];
    __syncthreads();
    int gid = blockIdx.x * 256 + threadIdx.x;
    int pixel = gid >> 2, q = gid & 3;
    int s = pixel >> 12;
    int pix = pixel & 4095;
    int h = pix >> 6, w = pix & 63;
    const float* p = tr + s * 12;
    float R0 = p[0], R1 = p[1], R2 = p[2],  t0 = p[3];
    float R3 = p[4], R4 = p[5], R5 = p[6],  t1 = p[7];
    float R6 = p[8], R7 = p[9], R8 = p[10], t2 = p[11];
    float xs = ((float)w - 31.5f) * RES;
    float ys = ((float)h - 31.5f) * RES;
    float p0x = fmaf(R0, xs, fmaf(R1, ys, t0)) + 31.5f;
    float p0y = fmaf(R3, xs, fmaf(R4, ys, t1)) + 31.5f;
    float p0z = fmaf(R6, xs, fmaf(R7, ys, t2)) + 31.5f;
    float a = 0.f;
#pragma unroll
    for (int j = 0; j < 7; ++j) {
        int k = q + 4 * j;
        if (k < 27) {
            float ox = (float)(k % 3 - 1), oy = (float)((k / 3) % 3 - 1), oz = (float)(k / 9 - 1);
            float px = p0x + ox * R0 + oy * R1 + oz * R2;
            float py = p0y + ox * R3 + oy * R4 + oz * R5;
            float pz = p0z + ox * R6 + oy * R7 + oz * R8;
            a = fmaf(s_psf[k], trilin_gather_bf(vin, px, py, pz), a);
        }
    }
    a += __shfl_xor(a, 1);
    a += __shfl_xor(a, 2);
    if (q == 0) g[pixel] = a;
}

// ---------------- block reduce -> one atomic ----------------
__device__ __forceinline__ void block_reduce_atomic(float v, float* dst) {
#pragma unroll
    for (int off = 32; off > 0; off >>= 1) v += __shfl_down(v, off, 64);
    __shared__ float s_red[4];
    int lane = threadIdx.x & 63, wid = threadIdx.x >> 6;
    if (lane == 0) s_red[wid] = v;
    __syncthreads();
    if (threadIdx.x == 0) atomicAdd(dst, s_red[0] + s_red[1] + s_red[2] + s_red[3]);
}

// ---------------------------------------------------------------
// Adjoint At: gather over voxel columns, 6-wide register z-window.
// Block = 4 columns x 64 slices; direct complete output + fused epilogue.
// MODE 0: vout = At(g)
// MODE 1: rv = aux - At(g); r = p = rv; scal += rr       (residual)
// MODE 2: vout = At(g); scal += dot(aux, vout)           (p.Ap)
// ---------------------------------------------------------------
template<int MODE>
__global__ __launch_bounds__(256) void k_atv(const float* __restrict__ g,
                                             float* __restrict__ vout,
                                             const float* __restrict__ tab,
                                             const float* __restrict__ aux,
                                             float* __restrict__ r,
                                             float* __restrict__ p,
                                             float* __restrict__ scal_dst) {
    __shared__ float cols[4][68];
    for (int i = threadIdx.x; i < 4 * 68; i += 256) (&cols[0][0])[i] = 0.f;
    __syncthreads();

    int lc = threadIdx.x & 3;
    int s  = threadIdx.x >> 2;          // 0..63
    int col0 = blockIdx.x * 4;
    int col = col0 + lc;
    float X = (float)(col & 63), Y = (float)(col >> 6);

    const float* tbase = tab + s * 27 * 16;
    int gbase = s << 12;

    // window base from center tap (k=13, ox=oy=oz=0)
    const float* ec = tbase + 13 * 16;
    float4 c0 = *(const float4*)(ec);
    float4 c1 = *(const float4*)(ec + 4);
    float4 c2 = *(const float4*)(ec + 8);
    float4 c3 = *(const float4*)(ec + 12);
    float rxc = X - c2.z, ryc = Y - c2.w;
    float wsc = c0.x * rxc + c0.y * ryc;
    float hsc = c0.z * rxc + c0.w * ryc;
    float pzc = fmaf(wsc, c1.z, fmaf(hsc, c2.y, c3.x));
    float basef = floorf(pzc) - 2.f;
    int   basei = (int)basef;

    float acc[WIN];
#pragma unroll
    for (int j = 0; j < WIN; ++j) acc[j] = 0.f;

    for (int k = 0; k < 27; ++k) {
        const float* e = tbase + k * 16;
        float4 e0 = *(const float4*)(e);
        float4 e1 = *(const float4*)(e + 4);
        float4 e2 = *(const float4*)(e + 8);
        float4 e3 = *(const float4*)(e + 12);
        float Ux = e1.x, Uy = e1.y, Uz = e1.z, Vx = e1.w;
        float Vy = e2.x, Vz = e2.y;
        float Cxr = e2.z - X, Cyr = e2.w - Y;   // C - voxel(x,y)
        float psfk = e3.y;
        float ws = e0.x * (-Cxr) + e0.y * (-Cyr);
        float hs = e0.z * (-Cxr) + e0.w * (-Cyr);
        float w0f = floorf(ws), h0f = floorf(hs);
        int w0 = (int)w0f, h0 = (int)h0f;
#pragma unroll
        for (int dh = 0; dh < 2; ++dh) {
            float fh = h0f + (float)dh;
            int hi = h0 + dh;
            int hok = ((unsigned)hi < 64u) ? 1 : 0;
            int hc = min(max(hi, 0), 63);
            float tx = fmaf(fh, Vx, Cxr);
            float ty = fmaf(fh, Vy, Cyr);
            float tz = fmaf(fh, Vz, e3.x);
#pragma unroll
            for (int dw = 0; dw < 2; ++dw) {
                float fw = w0f + (float)dw;
                int wi = w0 + dw;
                int ok = ((unsigned)wi < 64u) ? hok : 0;
                int wc = min(max(wi, 0), 63);
                float ddx = fmaf(fw, Ux, tx);          // px - X
                float ddy = fmaf(fw, Uy, ty);          // py - Y
                float wx = fmaxf(0.f, 1.f - fabsf(ddx));
                float wy = fmaxf(0.f, 1.f - fabsf(ddy));
                float gv = g[gbase + (hc << 6) + wc];
                float val = ok ? (wx * wy * psfk * gv) : 0.f;
                float prel = fmaf(fw, Uz, tz) - basef; // pz - base
#pragma unroll
                for (int j = 0; j < WIN; ++j) {
                    float t = fmaxf(0.f, 1.f - fabsf(prel - (float)j));
                    acc[j] = fmaf(val, t, acc[j]);
                }
            }
        }
    }

#pragma unroll
    for (int j = 0; j < WIN; ++j) {
        int zj = basei + j;
        int okz = ((unsigned)zj < 64u);
        int zc = min(max(zj, 0), 63);
        atomicAdd(&cols[lc][zc], okz ? acc[j] : 0.f);
    }
    __syncthreads();

    // fused epilogue: each thread owns one (z, col) voxel
    int z = threadIdx.x >> 2;
    int l2 = threadIdx.x & 3;
    int idx = (z << 12) + col0 + l2;
    float v = cols[l2][z];
    if (MODE == 0) {
        vout[idx] = v;
    } else if (MODE == 1) {
        float rv = aux[idx] - v;
        r[idx] = rv;
        p[idx] = rv;
        block_reduce_atomic(rv * rv, scal_dst);
    } else {
        vout[idx] = v;
        block_reduce_atomic(aux[idx] * v, scal_dst);
    }
}

// ---------------- CG updates ----------------

// alpha = scal[0]/scal[1]; x_out = x_in + alpha p; r -= alpha Ap; scal[2] += r.r
__global__ __launch_bounds__(256) void k_update_xr(const float* __restrict__ x_in,
                                                   float* __restrict__ x_out,
                                                   float* __restrict__ r,
                                                   const float* __restrict__ p,
                                                   const float* __restrict__ Ap,
                                                   float* __restrict__ scal) {
    int i = blockIdx.x * 256 + threadIdx.x;
    float alpha = scal[0] / scal[1];
    x_out[i] = fmaf(alpha, p[i], x_in[i]);
    float rv = fmaf(-alpha, Ap[i], r[i]);
    r[i] = rv;
    block_reduce_atomic(rv * rv, &scal[2]);
}

__global__ __launch_bounds__(256) void k_update_p(float* __restrict__ p,
                                                  const float* __restrict__ r,
                                                  const float* __restrict__ scal) {
    int i = blockIdx.x * 256 + threadIdx.x;
    float beta = scal[2] / scal[0];
    p[i] = fmaf(beta, p[i], r[i]);
}

__global__ __launch_bounds__(256) void k_final(const float* __restrict__ x,
                                               const float* __restrict__ p,
                                               const float* __restrict__ scal,
                                               float* __restrict__ out) {
    int i = blockIdx.x * 256 + threadIdx.x;
    float alpha = scal[2] / scal[3];
    float v = fmaf(alpha, p[i], x[i]);
    out[i] = v > 0.f ? v : 0.f;
}

extern "C" void kernel_launch(void* const* d_in, const int* in_sizes, int n_in,
                              void* d_out, int out_size, void* d_ws, size_t ws_size,
                              hipStream_t stream) {
    const float* transforms = (const float*)d_in[0];
    const float* slices     = (const float*)d_in[1];
    const float* volume     = (const float*)d_in[2];
    const float* psf        = (const float*)d_in[3];
    float* out = (float*)d_out;

    float* tab    = (float*)d_ws;             // 1728*16 floats
    float* vol_b  = tab    + NTAB * 16;
    float* vol_x  = vol_b  + NVOX;
    float* vol_r  = vol_x  + NVOX;
    float* vol_p  = vol_r  + NVOX;
    float* vol_Ap = vol_p  + NVOX;
    float* gbuf   = vol_Ap + NVOX;
    float* scal   = gbuf   + NPIX;            // 4 floats: rr0, pAp0, rr1, pAp1

    const int ablk = (NVOX / 64) / 4;         // 1024 (k_atv: 4 cols/block)
    const int fblk = NPIX * 4 / 256;          // 4096 (k_a: 4 lanes/pixel)
    const int vblk = NVOX / 256;              // 16

    hipMemsetAsync(scal, 0, 4 * sizeof(float), stream);

    k_setup<<<(NTAB + 255) / 256, 256, 0, stream>>>(transforms, psf, tab);

    // b = At(slices)
    k_atv<0><<<ablk, 256, 0, stream>>>(slices, vol_b, tab, nullptr, nullptr, nullptr, nullptr);

    // r = b - AtA(x0); p = r; rr0   (residual fused into adjoint)
    k_a<<<fblk, 256, 0, stream>>>(volume, gbuf, transforms, psf);
    k_atv<1><<<ablk, 256, 0, stream>>>(gbuf, nullptr, tab, vol_b, vol_r, vol_p, &scal[0]);

    // iter 0: Ap = AtA(p); pAp0 fused
    k_a<<<fblk, 256, 0, stream>>>(vol_p, gbuf, transforms, psf);
    k_atv<2><<<ablk, 256, 0, stream>>>(gbuf, vol_Ap, tab, vol_p, nullptr, nullptr, &scal[1]);
    k_update_xr<<<vblk, 256, 0, stream>>>(volume, vol_x, vol_r, vol_p, vol_Ap, scal);
    k_update_p<<<vblk, 256, 0, stream>>>(vol_p, vol_r, scal);

    // iter 1: pAp1 fused
    k_a<<<fblk, 256, 0, stream>>>(vol_p, gbuf, transforms, psf);
    k_atv<2><<<ablk, 256, 0, stream>>>(gbuf, vol_Ap, tab, vol_p, nullptr, nullptr, &scal[3]);
    k_final<<<vblk, 256, 0, stream>>>(vol_x, vol_p, scal, out);
}